// Round 8
// baseline (303.184 us; speedup 1.0000x reference)
//
#include <hip/hip_runtime.h>
#include <hip/hip_bf16.h>

using bf16 = __hip_bfloat16;
typedef __attribute__((ext_vector_type(8))) short short8;   // 8 x bf16 MFMA operand
typedef __attribute__((ext_vector_type(4))) float floatx4;  // MFMA accumulator

#define AS1 __attribute__((address_space(1)))
#define AS3 __attribute__((address_space(3)))

__device__ __forceinline__ floatx4 mfma16(short8 a, short8 b, floatx4 c) {
  return __builtin_amdgcn_mfma_f32_16x16x32_bf16(a, b, c, 0, 0, 0);
}
// async global->LDS, 16B per lane; LDS dest = wave-uniform base + lane*16
__device__ __forceinline__ void gload16(const bf16* g, bf16* l) {
  __builtin_amdgcn_global_load_lds((const AS1 unsigned*)g, (AS3 unsigned*)l, 16, 0, 0);
}
// packed f32x2 -> bf16x2 (low word = first arg), RNE like __float2bfloat16
__device__ __forceinline__ unsigned pk_bf16(float lo, float hi) {
  unsigned r;
  asm("v_cvt_pk_bf16_f32 %0, %1, %2" : "=v"(r) : "v"(lo), "v"(hi));
  return r;
}
// two-register lane swaps (gfx950)
__device__ __forceinline__ void swap32(unsigned& a, unsigned& b) {
  asm("v_permlane32_swap_b32 %0, %1" : "+v"(a), "+v"(b));
}
__device__ __forceinline__ void swap16(unsigned& a, unsigned& b) {
  asm("v_permlane16_swap_b32 %0, %1" : "+v"(a), "+v"(b));
}
__device__ __forceinline__ short8 mk_frag(unsigned w0, unsigned w1, unsigned w2,
                                          unsigned w3) {
  union { unsigned w[4]; short8 s; } r;
  r.w[0] = w0; r.w[1] = w1; r.w[2] = w2; r.w[3] = w3;
  return r.s;
}
__device__ __forceinline__ float b2f(unsigned short u) {
  union { float f; unsigned i; } x;
  x.i = ((unsigned)u) << 16;
  return x.f;
}

// ------------- fused fp32 -> bf16 casts for all 5 inputs (one launch) -------
__global__ void cast_all_k(const float* __restrict__ x, const float* __restrict__ Wq,
                           const float* __restrict__ Wk, const float* __restrict__ Wv,
                           const float* __restrict__ Wo, bf16* __restrict__ xb,
                           bf16* __restrict__ wqkv, bf16* __restrict__ wo_b) {
  int blk = blockIdx.x;
  const float* src;
  bf16* dst;
  int off;
  if (blk < 8192)       { src = x;  dst = xb;                 off = blk; }
  else if (blk < 12288) { src = Wq; dst = wqkv;               off = blk - 8192; }
  else if (blk < 13312) { src = Wk; dst = wqkv + 2048 * 2048; off = blk - 12288; }
  else if (blk < 14336) { src = Wv; dst = wqkv + 2560 * 2048; off = blk - 13312; }
  else                  { src = Wo; dst = wo_b;               off = blk - 14336; }
  int i = (off * 256 + threadIdx.x) * 4;
  float4 v = *(const float4*)(src + i);
  bf16 t[4] = {__float2bfloat16(v.x), __float2bfloat16(v.y),
               __float2bfloat16(v.z), __float2bfloat16(v.w)};
  *(ushort4*)(dst + i) = *(const ushort4*)t;
}

// ------- GEMM C[M,N] = A[M,K] * B[N,K]^T, bf16 in, OutT out (128x128 tile) ---
template <typename OutT>
__global__ __launch_bounds__(256, 2)
void gemm_bt(const bf16* __restrict__ A, const bf16* __restrict__ B,
             OutT* __restrict__ C, int M, int N, int K) {
  __shared__ alignas(16) bf16 As[128 * 32];
  __shared__ alignas(16) bf16 Bs[128 * 32];
  const int tid = threadIdx.x;
  const int w = tid >> 6, lane = tid & 63, l16 = lane & 15, quad = lane >> 4;
  const int bm = blockIdx.x << 7, bn = blockIdx.y << 7;
  const int wm = (w & 1) << 6, wn = (w >> 1) << 6;

  const int r = tid >> 2, p = tid & 3;
  const int g0 = (p ^ ((r >> 1) & 3)) << 3;            // source group (elems)
  const int g1 = (p ^ (((r + 64) >> 1) & 3)) << 3;
  const bf16* Ag0 = A + (long)(bm + r) * K + g0;
  const bf16* Ag1 = A + (long)(bm + r + 64) * K + g1;
  const bf16* Bg0 = B + (long)(bn + r) * K + g0;
  const bf16* Bg1 = B + (long)(bn + r + 64) * K + g1;
  bf16* Asw = As + (w << 9);  // wave LDS base (64 lanes * 8 elems)
  bf16* Bsw = Bs + (w << 9);

  floatx4 acc[4][4];
#pragma unroll
  for (int i = 0; i < 4; ++i)
#pragma unroll
    for (int j = 0; j < 4; ++j) acc[i][j] = (floatx4)(0.0f);

  for (int k0 = 0; k0 < K; k0 += 32) {
    gload16(Ag0 + k0, Asw);
    gload16(Ag1 + k0, Asw + 2048);
    gload16(Bg0 + k0, Bsw);
    gload16(Bg1 + k0, Bsw + 2048);
    __syncthreads();
    short8 af[4], bfv[4];
#pragma unroll
    for (int mi = 0; mi < 4; ++mi) {
      int row = wm + (mi << 4) + l16;
      int pos = quad ^ ((row >> 1) & 3);
      af[mi] = *(const short8*)(As + row * 32 + pos * 8);
    }
#pragma unroll
    for (int ni = 0; ni < 4; ++ni) {
      int row = wn + (ni << 4) + l16;
      int pos = quad ^ ((row >> 1) & 3);
      bfv[ni] = *(const short8*)(Bs + row * 32 + pos * 8);
    }
#pragma unroll
    for (int mi = 0; mi < 4; ++mi)
#pragma unroll
      for (int ni = 0; ni < 4; ++ni)
        acc[mi][ni] = mfma16(af[mi], bfv[ni], acc[mi][ni]);
    __syncthreads();
  }

#pragma unroll
  for (int mi = 0; mi < 4; ++mi)
#pragma unroll
    for (int ni = 0; ni < 4; ++ni)
#pragma unroll
      for (int rr = 0; rr < 4; ++rr) {
        int row = bm + wm + (mi << 4) + (quad << 2) + rr;  // C/D: row=quad*4+reg
        int col = bn + wn + (ni << 4) + l16;               //      col=lane&15
        float v = acc[mi][ni][rr];
        if constexpr (sizeof(OutT) == 2)
          C[(long)row * N + col] = __float2bfloat16(v);
        else
          C[(long)row * N + col] = v;
      }
}

// ---------------- RoPE: qkv[4096][3072] -> Q[B,H,S,DH]*scale, K[B,KVH,S,DH] ----
// Vectorized: each thread handles 8 rope pairs (d0..d0+7, +64) via short8 loads.
__global__ void rope_k(const bf16* __restrict__ qkv, bf16* __restrict__ Q,
                       bf16* __restrict__ Kd) {
  int idx = blockIdx.x * 256 + threadIdx.x;  // 4096 tok x 20 heads x 8 groups
  int g = idx & 7;
  int rest = idx >> 3;
  int head = rest % 20;
  int token = rest / 20;
  int s = token & 2047;
  int b = token >> 11;
  int d0 = g << 3;
  const float C0 = 0.20762050593046439f;  // log2(10000)/64
  float fs = (float)s;
  float cl[4], sl[4], ch[4], sh[4];
#pragma unroll
  for (int f = 0; f < 4; ++f) {
    float i1 = (float)((d0 >> 1) + f);
    float a1 = fs * exp2f(-i1 * C0);
    float a2 = fs * exp2f(-(i1 + 32.0f) * C0);
    __sincosf(a1, &sl[f], &cl[f]);
    __sincosf(a2, &sh[f], &ch[f]);
  }
  bool isq = head < 16;
  const bf16* p = qkv + (long)token * 3072 +
                  (isq ? head * 128 : 2048 + (head - 16) * 128) + d0;
  union U { short8 v; unsigned short u[8]; } lo, hi, olo, ohi;
  lo.v = *(const short8*)p;
  hi.v = *(const short8*)(p + 64);
  const float sc = isq ? 0.08838834764831845f * 1.4426950408889634f : 1.0f;
#pragma unroll
  for (int i = 0; i < 8; ++i) {
    int f = i >> 1;
    float xl = b2f(lo.u[i]), xh = b2f(hi.u[i]);
    bf16 vlo = __float2bfloat16((xl * cl[f] - xh * sl[f]) * sc);
    bf16 vhi = __float2bfloat16((xh * ch[f] + xl * sh[f]) * sc);
    olo.u[i] = *(const unsigned short*)&vlo;
    ohi.u[i] = *(const unsigned short*)&vhi;
  }
  bf16* dst = isq ? (Q + ((long)((b << 4) + head) * 2048 + s) * 128 + d0)
                  : (Kd + ((long)((b << 2) + (head - 16)) * 2048 + s) * 128 + d0);
  *(short8*)dst = olo.v;
  *(short8*)(dst + 64) = ohi.v;
}

// ---------------- V transpose: qkv V cols -> Vt[B,KVH,DH,S] ----------------
__global__ void vtrans_k(const bf16* __restrict__ qkv, bf16* __restrict__ Vt) {
  __shared__ bf16 t[32][33];
  int x = threadIdx.x, y = threadIdx.y;
  int s0 = blockIdx.x << 5, d0 = blockIdx.y << 5, bkv = blockIdx.z;
  int b = bkv >> 2, kvh = bkv & 3;
  const bf16* src = qkv + (long)((b << 11) + s0) * 3072 + 2560 + kvh * 128 + d0;
#pragma unroll
  for (int yy = y; yy < 32; yy += 8) t[yy][x] = src[(long)yy * 3072 + x];
  __syncthreads();
  bf16* dst = Vt + (long)((bkv << 7) + d0) * 2048 + s0;
#pragma unroll
  for (int yy = y; yy < 32; yy += 8) dst[(long)yy * 2048 + x] = t[x][yy];
}

// -------- flash attention: UNPAIRED q-tiles, BKV=32, 4-waves/block ----------
// One block = one 64-query q-tile t (queries [64t,64t+64)) of head bh; wave wl
// handles 16 queries 64t+16wl+l16. No A/B pairing -> 1024 blocks = 4096 waves;
// LDS 32KB (K[2][32x128] 16KB + V[2][128x32] 16KB) -> 4 blk/CU (VGPR-capped
// 16 waves/CU) = 4 waves/SIMD, double the paired kernel's 2. This is the
// occupancy experiment rounds 5-6 failed to run (launch-bounds spill; grid
// conservation). Cost: per-wave LDS-read:MFMA ratio doubles (~50% LDS busy).
// Keys: valid k <= q+128. Per-wave 32-key tiles: nk_w = min(2t+5+(wl>>1),64);
// single straddle tile jm = 2t+4+(wl>>1) (masked); block bound nkMax =
// min(2t+6,64); waves skip j >= nk_w (wave-uniform guard, no barrier inside).
// QK^T transposed (A=K, B=Q); P->PV redistribution in registers (cvt_pk +
// permlane swaps, same verified path as paired kcl=0). Double-buffered
// staging, prefetch j+1 over compute j. Grid remap: id&7 = (b<<2)|kvh pins
// each K/V set (L2-resident, reread by 128 blocks) to one XCD (T1); q-tiles
// interleaved t<->31-t for heavy/light balance.
__global__ __launch_bounds__(256, 4)
void attn_k(const bf16* __restrict__ Q, const bf16* __restrict__ K,
            const bf16* __restrict__ V, bf16* __restrict__ O) {
  __shared__ alignas(16) bf16 lk[2][32 * 128];  // [key][d]   8KB x2
  __shared__ alignas(16) bf16 lv[2][128 * 32];  // [d][key]   8KB x2
  const int tid = threadIdx.x, wl = tid >> 6, lane = tid & 63;
  const int l16 = lane & 15, quad = lane >> 4;
  const int id = blockIdx.x;                   // XCD-aware remap (bijective)
  const int xcd = id & 7;
  const int b = xcd >> 2, kvh = xcd & 3;
  const int rest = id >> 3;                    // 0..127
  const int h = (kvh << 2) | (rest & 3);
  const int u = rest >> 2;                     // 0..31
  const int t = (u & 1) ? (31 - (u >> 1)) : (u >> 1);  // heavy/light interleave
  const int bh = (b << 4) | h;
  const int q0 = t << 6;                       // block query base
  int nkMt = 2 * t + 6;
  const int nkMax = nkMt < 64 ? nkMt : 64;     // block loop bound
  int nkwt = 2 * t + 5 + (wl >> 1);
  const int nk_w = nkwt < 64 ? nkwt : 64;      // per-wave tile count
  const int jm = 2 * t + 4 + (wl >> 1);        // straddle tile (mask j >= jm)
  const bf16* Qp = Q + (long)bh * 2048 * 128;
  const bf16* Kp = K + (long)((b << 2) + kvh) * 2048 * 128;
  const bf16* Vp = V + (long)((b << 2) + kvh) * 128 * 2048;

  short8 qf[4];  // Q B-frags: n=l16(query), k=quad*8.., kc over DH/32
#pragma unroll
  for (int kc = 0; kc < 4; ++kc)
    qf[kc] = *(const short8*)(Qp + (long)(q0 + (wl << 4) + l16) * 128 + kc * 32 + quad * 8);

  floatx4 oA[8];
#pragma unroll
  for (int i = 0; i < 8; ++i) oA[i] = (floatx4)(0.0f);
  float lA = 0.0f;   // per-lane l for query l16 (summed over quads)

  // stage 32-key K/V tile j into buffer bufi (4 gload16 per thread, 256 thr)
  auto stage = [&](int j, int bufi) {
    const int k0 = j << 5;
    bf16* lkb = &lk[bufi][0];
    bf16* lvb = &lv[bufi][0];
#pragma unroll
    for (int i = 0; i < 2; ++i) {  // K [32 key][128 d]
      int c = i * 256 + tid;
      int row = c >> 4, pos = c & 15;
      int grp = (pos & 8) | ((pos & 7) ^ (row & 7));
      gload16(Kp + (long)(k0 + row) * 128 + grp * 8, lkb + (i * 256 + (wl << 6)) * 8);
    }
#pragma unroll
    for (int i = 0; i < 2; ++i) {  // V [128 d][32 key]
      int c = i * 256 + tid;
      int row = c >> 2, cg = c & 3;
      int grp = cg ^ (row & 3) ^ ((row >> 2) & 3);
      gload16(Vp + (long)row * 2048 + k0 + grp * 8, lvb + (i * 256 + (wl << 6)) * 8);
    }
  };

  auto tile = [&](int k0, bool maskT, int bufi) {
    const bf16* lkb = &lk[bufi][0];
    const bf16* lvb = &lv[bufi][0];
    floatx4 sA[2];
    sA[0] = (floatx4)(0.0f);
    sA[1] = (floatx4)(0.0f);
    // S^T = K*Q^T (A=K rows=keys, B=Q cols=queries)
    __builtin_amdgcn_s_setprio(1);
#pragma unroll
    for (int kc = 0; kc < 4; ++kc) {
#pragma unroll
      for (int kt = 0; kt < 2; ++kt) {
        int row = (kt << 4) + l16;
        int g = (kc << 2) + quad;
        int pos = (g & 8) | ((g & 7) ^ (row & 7));
        short8 kf = *(const short8*)(lkb + row * 128 + pos * 8);
        sA[kt] = mfma16(kf, qf[kc], sA[kt]);
      }
    }
    __builtin_amdgcn_s_setprio(0);
    // mask: S^T value (kt,rr): key = k0+kt*16+quad*4+rr, query = q0+wl*16+l16
    if (maskT) {
      int qg = q0 + (wl << 4) + l16 + 128;
#pragma unroll
      for (int kt = 0; kt < 2; ++kt)
#pragma unroll
        for (int rr = 0; rr < 4; ++rr) {
          int kg = k0 + (kt << 4) + (quad << 2) + rr;
          if (kg > qg) sA[kt][rr] = -1e30f;
        }
    }
    // exp2 + packed bf16x2 words, fully in registers
    unsigned wAp[2][2];
#pragma unroll
    for (int kt = 0; kt < 2; ++kt) {
      float p0 = exp2f(sA[kt][0]), p1 = exp2f(sA[kt][1]);
      float p2 = exp2f(sA[kt][2]), p3 = exp2f(sA[kt][3]);
      lA += (p0 + p1) + (p2 + p3);
      wAp[kt][0] = pk_bf16(p0, p1);
      wAp[kt][1] = pk_bf16(p2, p3);
    }
    // P A-fragment via permlane swaps (verified kcl=0 path of paired kernel)
    unsigned a0 = wAp[0][0], a1 = wAp[0][1];
    unsigned b0 = wAp[1][0], b1 = wAp[1][1];
    swap32(a0, b0); swap16(a0, b0);   // a0 = W0, b0 = W2
    swap32(a1, b1); swap16(a1, b1);   // a1 = W1, b1 = W3
    short8 pf = mk_frag(a0, a1, b0, b1);
    __builtin_amdgcn_s_setprio(1);
#pragma unroll
    for (int nd = 0; nd < 8; ++nd) {
      int vrow = (nd << 4) + l16;
      int vpos = quad ^ (vrow & 3) ^ ((vrow >> 2) & 3);
      short8 vf = *(const short8*)(lvb + vrow * 32 + (vpos << 3));
      oA[nd] = mfma16(pf, vf, oA[nd]);
    }
    __builtin_amdgcn_s_setprio(0);
  };

  stage(0, 0);
  __syncthreads();  // vmcnt(0) drain -> buf0 ready
  for (int j = 0; j < nkMax; ++j) {
    if (j + 1 < nkMax) stage(j + 1, (j + 1) & 1);  // prefetch overlaps compute
    if (j < nk_w)  // wave-uniform guard: short waves skip their extra tile
      tile(j << 5, j >= jm, j & 1);
    __syncthreads();  // drains prefetch (had full compute phase in flight)
  }

  // l: sum quads (lanes sharing l16), invert, redistribute to (quad,rr) rows
  lA += __shfl_xor(lA, 16, 64);
  lA += __shfl_xor(lA, 32, 64);
  float liA = 1.0f / lA;
  float rlA[4];
#pragma unroll
  for (int rr = 0; rr < 4; ++rr) rlA[rr] = __shfl(liA, (quad << 2) + rr, 64);

  bf16* Op = O + ((long)(b << 11) + q0 + (wl << 4)) * 2048 + (h << 7);
#pragma unroll
  for (int nd = 0; nd < 8; ++nd)
#pragma unroll
    for (int rr = 0; rr < 4; ++rr) {
      int row = (quad << 2) + rr;
      int col = (nd << 4) + l16;
      Op[(long)row * 2048 + col] = __float2bfloat16(oA[nd][rr] * rlA[rr]);
    }
}

extern "C" void kernel_launch(void* const* d_in, const int* in_sizes, int n_in,
                              void* d_out, int out_size, void* d_ws, size_t ws_size,
                              hipStream_t stream) {
  (void)in_sizes; (void)n_in; (void)out_size; (void)ws_size;
  const float* x  = (const float*)d_in[0];
  const float* Wq = (const float*)d_in[1];
  const float* Wk = (const float*)d_in[2];
  const float* Wv = (const float*)d_in[3];
  const float* Wo = (const float*)d_in[4];
  char* ws = (char*)d_ws;
  // ws layout (bytes): xb 16.7M | wqkv 12.6M | wo_b 8.4M | qkv 25.2M | Q 16.8M | K 4.2M | Vt 4.2M
  bf16* xb   = (bf16*)(ws);                 // also reused as Ob after gemm1
  bf16* wqkv = (bf16*)(ws + 16777216);
  bf16* wo_b = (bf16*)(ws + 29360128);
  bf16* qkv  = (bf16*)(ws + 37748736);
  bf16* Qr   = (bf16*)(ws + 62914560);
  bf16* Kr   = (bf16*)(ws + 79691776);
  bf16* Vt   = (bf16*)(ws + 83886080);
  bf16* Ob   = xb;  // x dead after QKV GEMM
  float* out = (float*)d_out;

  cast_all_k<<<18432, 256, 0, stream>>>(x, Wq, Wk, Wv, Wo, xb, wqkv, wo_b);

  gemm_bt<bf16><<<dim3(32, 24), 256, 0, stream>>>(xb, wqkv, qkv, 4096, 3072, 2048);
  rope_k<<<2560, 256, 0, stream>>>(qkv, Qr, Kr);
  vtrans_k<<<dim3(64, 4, 8), dim3(32, 8), 0, stream>>>(qkv, Vt);
  attn_k<<<dim3(1024), 256, 0, stream>>>(Qr, Kr, Vt, Ob);
  gemm_bt<float><<<dim3(32, 16), 256, 0, stream>>>(Ob, wo_b, out, 4096, 2048, 2048);
}

// Round 9
// 281.866 us; speedup vs baseline: 1.0756x; 1.0756x over previous
//
#include <hip/hip_runtime.h>
#include <hip/hip_bf16.h>

using bf16 = __hip_bfloat16;
typedef __attribute__((ext_vector_type(8))) short short8;   // 8 x bf16 MFMA operand
typedef __attribute__((ext_vector_type(4))) float floatx4;  // MFMA accumulator

#define AS1 __attribute__((address_space(1)))
#define AS3 __attribute__((address_space(3)))

__device__ __forceinline__ floatx4 mfma16(short8 a, short8 b, floatx4 c) {
  return __builtin_amdgcn_mfma_f32_16x16x32_bf16(a, b, c, 0, 0, 0);
}
// async global->LDS, 16B per lane; LDS dest = wave-uniform base + lane*16
__device__ __forceinline__ void gload16(const bf16* g, bf16* l) {
  __builtin_amdgcn_global_load_lds((const AS1 unsigned*)g, (AS3 unsigned*)l, 16, 0, 0);
}
// packed f32x2 -> bf16x2 (low word = first arg), RNE like __float2bfloat16
__device__ __forceinline__ unsigned pk_bf16(float lo, float hi) {
  unsigned r;
  asm("v_cvt_pk_bf16_f32 %0, %1, %2" : "=v"(r) : "v"(lo), "v"(hi));
  return r;
}
// two-register lane swaps (gfx950)
__device__ __forceinline__ void swap32(unsigned& a, unsigned& b) {
  asm("v_permlane32_swap_b32 %0, %1" : "+v"(a), "+v"(b));
}
__device__ __forceinline__ void swap16(unsigned& a, unsigned& b) {
  asm("v_permlane16_swap_b32 %0, %1" : "+v"(a), "+v"(b));
}
__device__ __forceinline__ short8 mk_frag(unsigned w0, unsigned w1, unsigned w2,
                                          unsigned w3) {
  union { unsigned w[4]; short8 s; } r;
  r.w[0] = w0; r.w[1] = w1; r.w[2] = w2; r.w[3] = w3;
  return r.s;
}
__device__ __forceinline__ float b2f(unsigned short u) {
  union { float f; unsigned i; } x;
  x.i = ((unsigned)u) << 16;
  return x.f;
}

// ------------- fused fp32 -> bf16 casts for all 5 inputs (one launch) -------
__global__ void cast_all_k(const float* __restrict__ x, const float* __restrict__ Wq,
                           const float* __restrict__ Wk, const float* __restrict__ Wv,
                           const float* __restrict__ Wo, bf16* __restrict__ xb,
                           bf16* __restrict__ wqkv, bf16* __restrict__ wo_b) {
  int blk = blockIdx.x;
  const float* src;
  bf16* dst;
  int off;
  if (blk < 8192)       { src = x;  dst = xb;                 off = blk; }
  else if (blk < 12288) { src = Wq; dst = wqkv;               off = blk - 8192; }
  else if (blk < 13312) { src = Wk; dst = wqkv + 2048 * 2048; off = blk - 12288; }
  else if (blk < 14336) { src = Wv; dst = wqkv + 2560 * 2048; off = blk - 13312; }
  else                  { src = Wo; dst = wo_b;               off = blk - 14336; }
  int i = (off * 256 + threadIdx.x) * 4;
  float4 v = *(const float4*)(src + i);
  bf16 t[4] = {__float2bfloat16(v.x), __float2bfloat16(v.y),
               __float2bfloat16(v.z), __float2bfloat16(v.w)};
  *(ushort4*)(dst + i) = *(const ushort4*)t;
}

// ------- GEMM C[M,N] = A[M,K] * B[N,K]^T, bf16 in, OutT out (128x128 tile) ---
// __launch_bounds__(256,3): 3 blocks/CU (12 waves, VGPR cap 170 >= 104 used;
// LDS 16KB x3 = 48KB). gemm1's 768-block grid = 3x256 -> ONE co-resident
// round (was 1.5 rounds at 2/CU: 512 + half-empty 256-block tail).
template <typename OutT>
__global__ __launch_bounds__(256, 3)
void gemm_bt(const bf16* __restrict__ A, const bf16* __restrict__ B,
             OutT* __restrict__ C, int M, int N, int K) {
  __shared__ alignas(16) bf16 As[128 * 32];
  __shared__ alignas(16) bf16 Bs[128 * 32];
  const int tid = threadIdx.x;
  const int w = tid >> 6, lane = tid & 63, l16 = lane & 15, quad = lane >> 4;
  const int bm = blockIdx.x << 7, bn = blockIdx.y << 7;
  const int wm = (w & 1) << 6, wn = (w >> 1) << 6;

  const int r = tid >> 2, p = tid & 3;
  const int g0 = (p ^ ((r >> 1) & 3)) << 3;            // source group (elems)
  const int g1 = (p ^ (((r + 64) >> 1) & 3)) << 3;
  const bf16* Ag0 = A + (long)(bm + r) * K + g0;
  const bf16* Ag1 = A + (long)(bm + r + 64) * K + g1;
  const bf16* Bg0 = B + (long)(bn + r) * K + g0;
  const bf16* Bg1 = B + (long)(bn + r + 64) * K + g1;
  bf16* Asw = As + (w << 9);  // wave LDS base (64 lanes * 8 elems)
  bf16* Bsw = Bs + (w << 9);

  floatx4 acc[4][4];
#pragma unroll
  for (int i = 0; i < 4; ++i)
#pragma unroll
    for (int j = 0; j < 4; ++j) acc[i][j] = (floatx4)(0.0f);

  for (int k0 = 0; k0 < K; k0 += 32) {
    gload16(Ag0 + k0, Asw);
    gload16(Ag1 + k0, Asw + 2048);
    gload16(Bg0 + k0, Bsw);
    gload16(Bg1 + k0, Bsw + 2048);
    __syncthreads();
    short8 af[4], bfv[4];
#pragma unroll
    for (int mi = 0; mi < 4; ++mi) {
      int row = wm + (mi << 4) + l16;
      int pos = quad ^ ((row >> 1) & 3);
      af[mi] = *(const short8*)(As + row * 32 + pos * 8);
    }
#pragma unroll
    for (int ni = 0; ni < 4; ++ni) {
      int row = wn + (ni << 4) + l16;
      int pos = quad ^ ((row >> 1) & 3);
      bfv[ni] = *(const short8*)(Bs + row * 32 + pos * 8);
    }
#pragma unroll
    for (int mi = 0; mi < 4; ++mi)
#pragma unroll
      for (int ni = 0; ni < 4; ++ni)
        acc[mi][ni] = mfma16(af[mi], bfv[ni], acc[mi][ni]);
    __syncthreads();
  }

#pragma unroll
  for (int mi = 0; mi < 4; ++mi)
#pragma unroll
    for (int ni = 0; ni < 4; ++ni)
#pragma unroll
      for (int rr = 0; rr < 4; ++rr) {
        int row = bm + wm + (mi << 4) + (quad << 2) + rr;  // C/D: row=quad*4+reg
        int col = bn + wn + (ni << 4) + l16;               //      col=lane&15
        float v = acc[mi][ni][rr];
        if constexpr (sizeof(OutT) == 2)
          C[(long)row * N + col] = __float2bfloat16(v);
        else
          C[(long)row * N + col] = v;
      }
}

// ---------------- RoPE: qkv[4096][3072] -> Q[B,H,S,DH]*scale, K[B,KVH,S,DH] ----
// Vectorized: each thread handles 8 rope pairs (d0..d0+7, +64) via short8 loads.
__global__ void rope_k(const bf16* __restrict__ qkv, bf16* __restrict__ Q,
                       bf16* __restrict__ Kd) {
  int idx = blockIdx.x * 256 + threadIdx.x;  // 4096 tok x 20 heads x 8 groups
  int g = idx & 7;
  int rest = idx >> 3;
  int head = rest % 20;
  int token = rest / 20;
  int s = token & 2047;
  int b = token >> 11;
  int d0 = g << 3;
  const float C0 = 0.20762050593046439f;  // log2(10000)/64
  float fs = (float)s;
  float cl[4], sl[4], ch[4], sh[4];
#pragma unroll
  for (int f = 0; f < 4; ++f) {
    float i1 = (float)((d0 >> 1) + f);
    float a1 = fs * exp2f(-i1 * C0);
    float a2 = fs * exp2f(-(i1 + 32.0f) * C0);
    __sincosf(a1, &sl[f], &cl[f]);
    __sincosf(a2, &sh[f], &ch[f]);
  }
  bool isq = head < 16;
  const bf16* p = qkv + (long)token * 3072 +
                  (isq ? head * 128 : 2048 + (head - 16) * 128) + d0;
  union U { short8 v; unsigned short u[8]; } lo, hi, olo, ohi;
  lo.v = *(const short8*)p;
  hi.v = *(const short8*)(p + 64);
  const float sc = isq ? 0.08838834764831845f * 1.4426950408889634f : 1.0f;
#pragma unroll
  for (int i = 0; i < 8; ++i) {
    int f = i >> 1;
    float xl = b2f(lo.u[i]), xh = b2f(hi.u[i]);
    bf16 vlo = __float2bfloat16((xl * cl[f] - xh * sl[f]) * sc);
    bf16 vhi = __float2bfloat16((xh * ch[f] + xl * sh[f]) * sc);
    olo.u[i] = *(const unsigned short*)&vlo;
    ohi.u[i] = *(const unsigned short*)&vhi;
  }
  bf16* dst = isq ? (Q + ((long)((b << 4) + head) * 2048 + s) * 128 + d0)
                  : (Kd + ((long)((b << 2) + (head - 16)) * 2048 + s) * 128 + d0);
  *(short8*)dst = olo.v;
  *(short8*)(dst + 64) = ohi.v;
}

// ---------------- V transpose: qkv V cols -> Vt[B,KVH,DH,S] ----------------
__global__ void vtrans_k(const bf16* __restrict__ qkv, bf16* __restrict__ Vt) {
  __shared__ bf16 t[32][33];
  int x = threadIdx.x, y = threadIdx.y;
  int s0 = blockIdx.x << 5, d0 = blockIdx.y << 5, bkv = blockIdx.z;
  int b = bkv >> 2, kvh = bkv & 3;
  const bf16* src = qkv + (long)((b << 11) + s0) * 3072 + 2560 + kvh * 128 + d0;
#pragma unroll
  for (int yy = y; yy < 32; yy += 8) t[yy][x] = src[(long)yy * 3072 + x];
  __syncthreads();
  bf16* dst = Vt + (long)((bkv << 7) + d0) * 2048 + s0;
#pragma unroll
  for (int yy = y; yy < 32; yy += 8) dst[(long)yy * 2048 + x] = t[x][yy];
}

// -------- flash attention: paired q-tiles, BKV=64, DOUBLE-BUFFERED staging --
// (round-2 proven version, 67.4us; FROZEN after occupancy experiments r5-r7
// showed the dual-idle gap is intra-wave latency: merged-512thr = no change,
// unpaired-BKV32 = regression from doubled LDS ratio + conflicts.)
// mask: key k valid iff k <= q + 128. Block bx: q-tiles A=bx (light), B=31-bx
// (heavy); 64-key tiles: nkA=bx+3, nkB=min(34-bx,32); straddle masks at
// jmA=bx+2, jmB=33-bx. Prefetch tile j+1 into buf[(j+1)&1] while computing
// tile j. QK^T transposed (A=K, B=Q); P->PV redistribution fully in registers
// (cvt_pk + permlane swaps). Grid: 512 blocks remapped so id&7 = (b<<2)|kvh
// pins each K/V working set (1MB, L2-fits) to one XCD (T1).
__global__ __launch_bounds__(256, 2)
void attn_k(const bf16* __restrict__ Q, const bf16* __restrict__ K,
            const bf16* __restrict__ V, bf16* __restrict__ O) {
  __shared__ alignas(16) bf16 lk[2][64 * 128];  // [key][d]   16KB x2
  __shared__ alignas(16) bf16 lv[2][128 * 64];  // [d][key]   16KB x2
  const int tid = threadIdx.x, w = tid >> 6, lane = tid & 63;
  const int l16 = lane & 15, quad = lane >> 4;
  const int id = blockIdx.x;                   // XCD-aware remap (bijective)
  const int xcd = id & 7;
  const int b = xcd >> 2, kvh = xcd & 3;
  const int rem = id >> 3;
  const int bx = rem >> 2;
  const int h = (kvh << 2) | (rem & 3);
  const int bh = (b << 4) | h;
  const int qa0 = bx << 6, qb0 = (31 - bx) << 6;
  const int nkA = bx + 3;                      // <= 18
  int nkBt = 34 - bx;
  const int nkB = nkBt < 32 ? nkBt : 32;       // clip at S/64
  const int jmA = bx + 2, jmB = 33 - bx;       // straddle tiles
  const bf16* Qp = Q + (long)bh * 2048 * 128;
  const bf16* Kp = K + (long)((b << 2) + kvh) * 2048 * 128;
  const bf16* Vp = V + (long)((b << 2) + kvh) * 128 * 2048;

  short8 qfA[4], qfB[4];  // Q B-frags: n=l16(query), k=quad*8.., kc over DH/32
#pragma unroll
  for (int kc = 0; kc < 4; ++kc) {
    qfA[kc] = *(const short8*)(Qp + (long)(qa0 + (w << 4) + l16) * 128 + kc * 32 + quad * 8);
    qfB[kc] = *(const short8*)(Qp + (long)(qb0 + (w << 4) + l16) * 128 + kc * 32 + quad * 8);
  }

  floatx4 oA[8], oB[8];
#pragma unroll
  for (int i = 0; i < 8; ++i) { oA[i] = (floatx4)(0.0f); oB[i] = (floatx4)(0.0f); }
  float lA = 0.0f, lB = 0.0f;   // per-lane l for query l16 (summed over quads)

  // stage 64-key K/V tile j into buffer bufi (8 gload16 per thread)
  auto stage = [&](int j, int bufi) {
    const int k0 = j << 6;
    bf16* lkb = &lk[bufi][0];
    bf16* lvb = &lv[bufi][0];
#pragma unroll
    for (int i = 0; i < 4; ++i) {  // K [64][128]
      int c = i * 256 + tid;
      int row = c >> 4, pos = c & 15;
      int grp = (pos & 8) | ((pos & 7) ^ (row & 7));
      gload16(Kp + (long)(k0 + row) * 128 + grp * 8, lkb + (i * 256 + (w << 6)) * 8);
    }
#pragma unroll
    for (int i = 0; i < 4; ++i) {  // V [128 d][64 k]
      int c = i * 256 + tid;
      int row = c >> 3, grp = (c & 7) ^ (row & 7);
      gload16(Vp + (long)row * 2048 + k0 + grp * 8, lvb + (i * 256 + (w << 6)) * 8);
    }
  };

  auto tile = [&](auto bothc, int k0, bool maskA, bool maskB, int bufi) {
    constexpr bool BOTH = decltype(bothc)::value;
    const bf16* lkb = &lk[bufi][0];
    const bf16* lvb = &lv[bufi][0];
    floatx4 sA[4], sB[4];
#pragma unroll
    for (int kt = 0; kt < 4; ++kt) {
      sB[kt] = (floatx4)(0.0f);
      if constexpr (BOTH) sA[kt] = (floatx4)(0.0f);
    }
    // S^T = K*Q^T: shared kf (A-operand, m=key) feeds both query tiles
    __builtin_amdgcn_s_setprio(1);
#pragma unroll
    for (int kc = 0; kc < 4; ++kc) {
#pragma unroll
      for (int kt = 0; kt < 4; ++kt) {
        int row = (kt << 4) + l16;
        int g = (kc << 2) + quad;
        int pos = (g & 8) | ((g & 7) ^ (row & 7));
        short8 kf = *(const short8*)(lkb + row * 128 + pos * 8);
        sB[kt] = mfma16(kf, qfB[kc], sB[kt]);
        if constexpr (BOTH) sA[kt] = mfma16(kf, qfA[kc], sA[kt]);
      }
    }
    __builtin_amdgcn_s_setprio(0);
    // mask: S^T value (kt,rr): key = k0+kt*16+quad*4+rr, query = qX0+w*16+l16
    if (maskB) {
      int qg = qb0 + (w << 4) + l16 + 128;
#pragma unroll
      for (int kt = 0; kt < 4; ++kt)
#pragma unroll
        for (int rr = 0; rr < 4; ++rr) {
          int kg = k0 + (kt << 4) + (quad << 2) + rr;
          if (kg > qg) sB[kt][rr] = -1e30f;
        }
    }
    if constexpr (BOTH) {
      if (maskA) {
        int qg = qa0 + (w << 4) + l16 + 128;
#pragma unroll
        for (int kt = 0; kt < 4; ++kt)
#pragma unroll
          for (int rr = 0; rr < 4; ++rr) {
            int kg = k0 + (kt << 4) + (quad << 2) + rr;
            if (kg > qg) sA[kt][rr] = -1e30f;
          }
      }
    }
    // exp2 + packed bf16x2 words, fully in registers
    unsigned wBp[4][2], wAp[4][2];
#pragma unroll
    for (int kt = 0; kt < 4; ++kt) {
      float p0 = exp2f(sB[kt][0]), p1 = exp2f(sB[kt][1]);
      float p2 = exp2f(sB[kt][2]), p3 = exp2f(sB[kt][3]);
      lB += (p0 + p1) + (p2 + p3);
      wBp[kt][0] = pk_bf16(p0, p1);
      wBp[kt][1] = pk_bf16(p2, p3);
      if constexpr (BOTH) {
        float a0 = exp2f(sA[kt][0]), a1 = exp2f(sA[kt][1]);
        float a2 = exp2f(sA[kt][2]), a3 = exp2f(sA[kt][3]);
        lA += (a0 + a1) + (a2 + a3);
        wAp[kt][0] = pk_bf16(a0, a1);
        wAp[kt][1] = pk_bf16(a2, a3);
      }
    }
    // PV: build P A-fragments via permlane swaps; shared vf feeds both
#pragma unroll
    for (int kcl = 0; kcl < 2; ++kcl) {
      unsigned a0 = wBp[2 * kcl][0], a1 = wBp[2 * kcl][1];
      unsigned b0 = wBp[2 * kcl + 1][0], b1 = wBp[2 * kcl + 1][1];
      swap32(a0, b0); swap16(a0, b0);   // a0 = W0, b0 = W2
      swap32(a1, b1); swap16(a1, b1);   // a1 = W1, b1 = W3
      short8 pfB = mk_frag(a0, a1, b0, b1);
      short8 pfA;
      if constexpr (BOTH) {
        unsigned c0 = wAp[2 * kcl][0], c1 = wAp[2 * kcl][1];
        unsigned d0 = wAp[2 * kcl + 1][0], d1 = wAp[2 * kcl + 1][1];
        swap32(c0, d0); swap16(c0, d0);
        swap32(c1, d1); swap16(c1, d1);
        pfA = mk_frag(c0, c1, d0, d1);
      }
      int g = (kcl << 2) + quad;
      __builtin_amdgcn_s_setprio(1);
#pragma unroll
      for (int nd = 0; nd < 8; ++nd) {
        int vrow = (nd << 4) + l16;
        int vpos = g ^ (vrow & 7);
        short8 vf = *(const short8*)(lvb + vrow * 64 + (vpos << 3));
        oB[nd] = mfma16(pfB, vf, oB[nd]);
        if constexpr (BOTH) oA[nd] = mfma16(pfA, vf, oA[nd]);
      }
      __builtin_amdgcn_s_setprio(0);
    }
  };

  stage(0, 0);
  __syncthreads();  // vmcnt(0) drain -> buf0 ready
  for (int j = 0; j < nkB; ++j) {
    if (j + 1 < nkB) stage(j + 1, (j + 1) & 1);  // prefetch overlaps compute
    const int k0 = j << 6;
    if (j < nkA)
      tile(std::integral_constant<bool, true>{}, k0, j == jmA, j == jmB, j & 1);
    else
      tile(std::integral_constant<bool, false>{}, k0, false, j == jmB, j & 1);
    __syncthreads();  // drains prefetch (had full compute phase in flight)
  }

  // l: sum quads (lanes sharing l16), invert, redistribute to (quad,rr) rows
  lA += __shfl_xor(lA, 16, 64); lA += __shfl_xor(lA, 32, 64);
  lB += __shfl_xor(lB, 16, 64); lB += __shfl_xor(lB, 32, 64);
  float liA = 1.0f / lA, liB = 1.0f / lB;
  float rlA[4], rlB[4];
#pragma unroll
  for (int rr = 0; rr < 4; ++rr) {
    int src = (quad << 2) + rr;
    rlA[rr] = __shfl(liA, src, 64);
    rlB[rr] = __shfl(liB, src, 64);
  }

  bf16* OpA = O + ((long)(b << 11) + qa0 + (w << 4)) * 2048 + (h << 7);
  bf16* OpB = O + ((long)(b << 11) + qb0 + (w << 4)) * 2048 + (h << 7);
#pragma unroll
  for (int nd = 0; nd < 8; ++nd)
#pragma unroll
    for (int rr = 0; rr < 4; ++rr) {
      int row = (quad << 2) + rr;
      int col = (nd << 4) + l16;
      OpA[(long)row * 2048 + col] = __float2bfloat16(oA[nd][rr] * rlA[rr]);
      OpB[(long)row * 2048 + col] = __float2bfloat16(oB[nd][rr] * rlB[rr]);
    }
}

extern "C" void kernel_launch(void* const* d_in, const int* in_sizes, int n_in,
                              void* d_out, int out_size, void* d_ws, size_t ws_size,
                              hipStream_t stream) {
  (void)in_sizes; (void)n_in; (void)out_size; (void)ws_size;
  const float* x  = (const float*)d_in[0];
  const float* Wq = (const float*)d_in[1];
  const float* Wk = (const float*)d_in[2];
  const float* Wv = (const float*)d_in[3];
  const float* Wo = (const float*)d_in[4];
  char* ws = (char*)d_ws;
  // ws layout (bytes): xb 16.7M | wqkv 12.6M | wo_b 8.4M | qkv 25.2M | Q 16.8M | K 4.2M | Vt 4.2M
  bf16* xb   = (bf16*)(ws);                 // also reused as Ob after gemm1
  bf16* wqkv = (bf16*)(ws + 16777216);
  bf16* wo_b = (bf16*)(ws + 29360128);
  bf16* qkv  = (bf16*)(ws + 37748736);
  bf16* Qr   = (bf16*)(ws + 62914560);
  bf16* Kr   = (bf16*)(ws + 79691776);
  bf16* Vt   = (bf16*)(ws + 83886080);
  bf16* Ob   = xb;  // x dead after QKV GEMM
  float* out = (float*)d_out;

  cast_all_k<<<18432, 256, 0, stream>>>(x, Wq, Wk, Wv, Wo, xb, wqkv, wo_b);

  gemm_bt<bf16><<<dim3(32, 24), 256, 0, stream>>>(xb, wqkv, qkv, 4096, 3072, 2048);
  rope_k<<<2560, 256, 0, stream>>>(qkv, Qr, Kr);
  vtrans_k<<<dim3(64, 4, 8), dim3(32, 8), 0, stream>>>(qkv, Vt);
  attn_k<<<dim3(512), 256, 0, stream>>>(Qr, Kr, Vt, Ob);
  gemm_bt<float><<<dim3(32, 16), 256, 0, stream>>>(Ob, wo_b, out, 4096, 2048, 2048);
}

// Round 10
// 279.867 us; speedup vs baseline: 1.0833x; 1.0071x over previous
//
#include <hip/hip_runtime.h>
#include <hip/hip_bf16.h>

using bf16 = __hip_bfloat16;
typedef __attribute__((ext_vector_type(8))) short short8;   // 8 x bf16 MFMA operand
typedef __attribute__((ext_vector_type(4))) float floatx4;  // MFMA accumulator

#define AS1 __attribute__((address_space(1)))
#define AS3 __attribute__((address_space(3)))

__device__ __forceinline__ floatx4 mfma16(short8 a, short8 b, floatx4 c) {
  return __builtin_amdgcn_mfma_f32_16x16x32_bf16(a, b, c, 0, 0, 0);
}
// async global->LDS, 16B per lane; LDS dest = wave-uniform base + lane*16
__device__ __forceinline__ void gload16(const bf16* g, bf16* l) {
  __builtin_amdgcn_global_load_lds((const AS1 unsigned*)g, (AS3 unsigned*)l, 16, 0, 0);
}
// packed f32x2 -> bf16x2 (low word = first arg), RNE like __float2bfloat16
__device__ __forceinline__ unsigned pk_bf16(float lo, float hi) {
  unsigned r;
  asm("v_cvt_pk_bf16_f32 %0, %1, %2" : "=v"(r) : "v"(lo), "v"(hi));
  return r;
}
// two-register lane swaps (gfx950)
__device__ __forceinline__ void swap32(unsigned& a, unsigned& b) {
  asm("v_permlane32_swap_b32 %0, %1" : "+v"(a), "+v"(b));
}
__device__ __forceinline__ void swap16(unsigned& a, unsigned& b) {
  asm("v_permlane16_swap_b32 %0, %1" : "+v"(a), "+v"(b));
}
__device__ __forceinline__ short8 mk_frag(unsigned w0, unsigned w1, unsigned w2,
                                          unsigned w3) {
  union { unsigned w[4]; short8 s; } r;
  r.w[0] = w0; r.w[1] = w1; r.w[2] = w2; r.w[3] = w3;
  return r.s;
}
__device__ __forceinline__ float b2f(unsigned short u) {
  union { float f; unsigned i; } x;
  x.i = ((unsigned)u) << 16;
  return x.f;
}

// ------------- fused fp32 -> bf16 casts for all 5 inputs (one launch) -------
__global__ void cast_all_k(const float* __restrict__ x, const float* __restrict__ Wq,
                           const float* __restrict__ Wk, const float* __restrict__ Wv,
                           const float* __restrict__ Wo, bf16* __restrict__ xb,
                           bf16* __restrict__ wqkv, bf16* __restrict__ wo_b) {
  int blk = blockIdx.x;
  const float* src;
  bf16* dst;
  int off;
  if (blk < 8192)       { src = x;  dst = xb;                 off = blk; }
  else if (blk < 12288) { src = Wq; dst = wqkv;               off = blk - 8192; }
  else if (blk < 13312) { src = Wk; dst = wqkv + 2048 * 2048; off = blk - 12288; }
  else if (blk < 14336) { src = Wv; dst = wqkv + 2560 * 2048; off = blk - 13312; }
  else                  { src = Wo; dst = wo_b;               off = blk - 14336; }
  int i = (off * 256 + threadIdx.x) * 4;
  float4 v = *(const float4*)(src + i);
  bf16 t[4] = {__float2bfloat16(v.x), __float2bfloat16(v.y),
               __float2bfloat16(v.z), __float2bfloat16(v.w)};
  *(ushort4*)(dst + i) = *(const ushort4*)t;
}

// ------- GEMM C[M,N] = A[M,K] * B[N,K]^T, bf16 in, OutT out (128x128 tile) ---
// (256,3) measured neutral vs (256,2) in r8; kernel is pipe-limited ~780 TF
// (m97-structure ceiling), not tail-round-bound. Kept.
template <typename OutT>
__global__ __launch_bounds__(256, 3)
void gemm_bt(const bf16* __restrict__ A, const bf16* __restrict__ B,
             OutT* __restrict__ C, int M, int N, int K) {
  __shared__ alignas(16) bf16 As[128 * 32];
  __shared__ alignas(16) bf16 Bs[128 * 32];
  const int tid = threadIdx.x;
  const int w = tid >> 6, lane = tid & 63, l16 = lane & 15, quad = lane >> 4;
  const int bm = blockIdx.x << 7, bn = blockIdx.y << 7;
  const int wm = (w & 1) << 6, wn = (w >> 1) << 6;

  const int r = tid >> 2, p = tid & 3;
  const int g0 = (p ^ ((r >> 1) & 3)) << 3;            // source group (elems)
  const int g1 = (p ^ (((r + 64) >> 1) & 3)) << 3;
  const bf16* Ag0 = A + (long)(bm + r) * K + g0;
  const bf16* Ag1 = A + (long)(bm + r + 64) * K + g1;
  const bf16* Bg0 = B + (long)(bn + r) * K + g0;
  const bf16* Bg1 = B + (long)(bn + r + 64) * K + g1;
  bf16* Asw = As + (w << 9);  // wave LDS base (64 lanes * 8 elems)
  bf16* Bsw = Bs + (w << 9);

  floatx4 acc[4][4];
#pragma unroll
  for (int i = 0; i < 4; ++i)
#pragma unroll
    for (int j = 0; j < 4; ++j) acc[i][j] = (floatx4)(0.0f);

  for (int k0 = 0; k0 < K; k0 += 32) {
    gload16(Ag0 + k0, Asw);
    gload16(Ag1 + k0, Asw + 2048);
    gload16(Bg0 + k0, Bsw);
    gload16(Bg1 + k0, Bsw + 2048);
    __syncthreads();
    short8 af[4], bfv[4];
#pragma unroll
    for (int mi = 0; mi < 4; ++mi) {
      int row = wm + (mi << 4) + l16;
      int pos = quad ^ ((row >> 1) & 3);
      af[mi] = *(const short8*)(As + row * 32 + pos * 8);
    }
#pragma unroll
    for (int ni = 0; ni < 4; ++ni) {
      int row = wn + (ni << 4) + l16;
      int pos = quad ^ ((row >> 1) & 3);
      bfv[ni] = *(const short8*)(Bs + row * 32 + pos * 8);
    }
#pragma unroll
    for (int mi = 0; mi < 4; ++mi)
#pragma unroll
      for (int ni = 0; ni < 4; ++ni)
        acc[mi][ni] = mfma16(af[mi], bfv[ni], acc[mi][ni]);
    __syncthreads();
  }

#pragma unroll
  for (int mi = 0; mi < 4; ++mi)
#pragma unroll
    for (int ni = 0; ni < 4; ++ni)
#pragma unroll
      for (int rr = 0; rr < 4; ++rr) {
        int row = bm + wm + (mi << 4) + (quad << 2) + rr;  // C/D: row=quad*4+reg
        int col = bn + wn + (ni << 4) + l16;               //      col=lane&15
        float v = acc[mi][ni][rr];
        if constexpr (sizeof(OutT) == 2)
          C[(long)row * N + col] = __float2bfloat16(v);
        else
          C[(long)row * N + col] = v;
      }
}

// ------- merged RoPE + V-transpose (both read only qkv; one launch) ---------
// blocks [0,2560): RoPE  qkv -> Q[B,H,S,DH]*scale, K[B,KVH,S,DH]
//   (vectorized: 8 rope pairs/thread via short8; 4 shared freq groups)
// blocks [2560,4608): V transpose  qkv V cols -> Vt[B,KVH,DH,S]
//   (old dim3(64,4,8)/dim3(32,8) remapped onto flat grid/256-thr blocks)
// Bodies bit-identical to the previously-verified separate kernels.
__global__ void rope_vt_k(const bf16* __restrict__ qkv, bf16* __restrict__ Q,
                          bf16* __restrict__ Kd, bf16* __restrict__ Vt) {
  const int blk = blockIdx.x;
  if (blk < 2560) {
    // ---------------- RoPE path ----------------
    int idx = blk * 256 + threadIdx.x;  // 4096 tok x 20 heads x 8 groups
    int g = idx & 7;
    int rest = idx >> 3;
    int head = rest % 20;
    int token = rest / 20;
    int s = token & 2047;
    int b = token >> 11;
    int d0 = g << 3;
    const float C0 = 0.20762050593046439f;  // log2(10000)/64
    float fs = (float)s;
    float cl[4], sl[4], ch[4], sh[4];
#pragma unroll
    for (int f = 0; f < 4; ++f) {
      float i1 = (float)((d0 >> 1) + f);
      float a1 = fs * exp2f(-i1 * C0);
      float a2 = fs * exp2f(-(i1 + 32.0f) * C0);
      __sincosf(a1, &sl[f], &cl[f]);
      __sincosf(a2, &sh[f], &ch[f]);
    }
    bool isq = head < 16;
    const bf16* p = qkv + (long)token * 3072 +
                    (isq ? head * 128 : 2048 + (head - 16) * 128) + d0;
    union U { short8 v; unsigned short u[8]; } lo, hi, olo, ohi;
    lo.v = *(const short8*)p;
    hi.v = *(const short8*)(p + 64);
    const float sc = isq ? 0.08838834764831845f * 1.4426950408889634f : 1.0f;
#pragma unroll
    for (int i = 0; i < 8; ++i) {
      int f = i >> 1;
      float xl = b2f(lo.u[i]), xh = b2f(hi.u[i]);
      bf16 vlo = __float2bfloat16((xl * cl[f] - xh * sl[f]) * sc);
      bf16 vhi = __float2bfloat16((xh * ch[f] + xl * sh[f]) * sc);
      olo.u[i] = *(const unsigned short*)&vlo;
      ohi.u[i] = *(const unsigned short*)&vhi;
    }
    bf16* dst = isq ? (Q + ((long)((b << 4) + head) * 2048 + s) * 128 + d0)
                    : (Kd + ((long)((b << 2) + (head - 16)) * 2048 + s) * 128 + d0);
    *(short8*)dst = olo.v;
    *(short8*)(dst + 64) = ohi.v;
  } else {
    // ---------------- V-transpose path ----------------
    __shared__ bf16 t[32][33];
    const int vid = blk - 2560;              // old grid dim3(64,4,8)
    const int sx = vid & 63;
    const int dy = (vid >> 6) & 3;
    const int bkv = vid >> 8;
    const int x = threadIdx.x & 31, y = threadIdx.x >> 5;  // old block dim3(32,8)
    const int s0 = sx << 5, d0 = dy << 5;
    const int b = bkv >> 2, kvh = bkv & 3;
    const bf16* src = qkv + (long)((b << 11) + s0) * 3072 + 2560 + kvh * 128 + d0;
#pragma unroll
    for (int yy = y; yy < 32; yy += 8) t[yy][x] = src[(long)yy * 3072 + x];
    __syncthreads();
    bf16* dst = Vt + (long)((bkv << 7) + d0) * 2048 + s0;
#pragma unroll
    for (int yy = y; yy < 32; yy += 8) dst[(long)yy * 2048 + x] = t[x][yy];
  }
}

// -------- flash attention: paired q-tiles, BKV=64, DOUBLE-BUFFERED staging --
// (round-2 proven version, 67.4us; FROZEN after occupancy experiments r5-r7
// showed the dual-idle gap is intra-wave latency: merged-512thr = no change,
// unpaired-BKV32 = regression from doubled LDS ratio + conflicts.)
// mask: key k valid iff k <= q + 128. Block bx: q-tiles A=bx (light), B=31-bx
// (heavy); 64-key tiles: nkA=bx+3, nkB=min(34-bx,32); straddle masks at
// jmA=bx+2, jmB=33-bx. Prefetch tile j+1 into buf[(j+1)&1] while computing
// tile j. QK^T transposed (A=K, B=Q); P->PV redistribution fully in registers
// (cvt_pk + permlane swaps). Grid: 512 blocks remapped so id&7 = (b<<2)|kvh
// pins each K/V working set (1MB, L2-fits) to one XCD (T1).
__global__ __launch_bounds__(256, 2)
void attn_k(const bf16* __restrict__ Q, const bf16* __restrict__ K,
            const bf16* __restrict__ V, bf16* __restrict__ O) {
  __shared__ alignas(16) bf16 lk[2][64 * 128];  // [key][d]   16KB x2
  __shared__ alignas(16) bf16 lv[2][128 * 64];  // [d][key]   16KB x2
  const int tid = threadIdx.x, w = tid >> 6, lane = tid & 63;
  const int l16 = lane & 15, quad = lane >> 4;
  const int id = blockIdx.x;                   // XCD-aware remap (bijective)
  const int xcd = id & 7;
  const int b = xcd >> 2, kvh = xcd & 3;
  const int rem = id >> 3;
  const int bx = rem >> 2;
  const int h = (kvh << 2) | (rem & 3);
  const int bh = (b << 4) | h;
  const int qa0 = bx << 6, qb0 = (31 - bx) << 6;
  const int nkA = bx + 3;                      // <= 18
  int nkBt = 34 - bx;
  const int nkB = nkBt < 32 ? nkBt : 32;       // clip at S/64
  const int jmA = bx + 2, jmB = 33 - bx;       // straddle tiles
  const bf16* Qp = Q + (long)bh * 2048 * 128;
  const bf16* Kp = K + (long)((b << 2) + kvh) * 2048 * 128;
  const bf16* Vp = V + (long)((b << 2) + kvh) * 128 * 2048;

  short8 qfA[4], qfB[4];  // Q B-frags: n=l16(query), k=quad*8.., kc over DH/32
#pragma unroll
  for (int kc = 0; kc < 4; ++kc) {
    qfA[kc] = *(const short8*)(Qp + (long)(qa0 + (w << 4) + l16) * 128 + kc * 32 + quad * 8);
    qfB[kc] = *(const short8*)(Qp + (long)(qb0 + (w << 4) + l16) * 128 + kc * 32 + quad * 8);
  }

  floatx4 oA[8], oB[8];
#pragma unroll
  for (int i = 0; i < 8; ++i) { oA[i] = (floatx4)(0.0f); oB[i] = (floatx4)(0.0f); }
  float lA = 0.0f, lB = 0.0f;   // per-lane l for query l16 (summed over quads)

  // stage 64-key K/V tile j into buffer bufi (8 gload16 per thread)
  auto stage = [&](int j, int bufi) {
    const int k0 = j << 6;
    bf16* lkb = &lk[bufi][0];
    bf16* lvb = &lv[bufi][0];
#pragma unroll
    for (int i = 0; i < 4; ++i) {  // K [64][128]
      int c = i * 256 + tid;
      int row = c >> 4, pos = c & 15;
      int grp = (pos & 8) | ((pos & 7) ^ (row & 7));
      gload16(Kp + (long)(k0 + row) * 128 + grp * 8, lkb + (i * 256 + (w << 6)) * 8);
    }
#pragma unroll
    for (int i = 0; i < 4; ++i) {  // V [128 d][64 k]
      int c = i * 256 + tid;
      int row = c >> 3, grp = (c & 7) ^ (row & 7);
      gload16(Vp + (long)row * 2048 + k0 + grp * 8, lvb + (i * 256 + (w << 6)) * 8);
    }
  };

  auto tile = [&](auto bothc, int k0, bool maskA, bool maskB, int bufi) {
    constexpr bool BOTH = decltype(bothc)::value;
    const bf16* lkb = &lk[bufi][0];
    const bf16* lvb = &lv[bufi][0];
    floatx4 sA[4], sB[4];
#pragma unroll
    for (int kt = 0; kt < 4; ++kt) {
      sB[kt] = (floatx4)(0.0f);
      if constexpr (BOTH) sA[kt] = (floatx4)(0.0f);
    }
    // S^T = K*Q^T: shared kf (A-operand, m=key) feeds both query tiles
    __builtin_amdgcn_s_setprio(1);
#pragma unroll
    for (int kc = 0; kc < 4; ++kc) {
#pragma unroll
      for (int kt = 0; kt < 4; ++kt) {
        int row = (kt << 4) + l16;
        int g = (kc << 2) + quad;
        int pos = (g & 8) | ((g & 7) ^ (row & 7));
        short8 kf = *(const short8*)(lkb + row * 128 + pos * 8);
        sB[kt] = mfma16(kf, qfB[kc], sB[kt]);
        if constexpr (BOTH) sA[kt] = mfma16(kf, qfA[kc], sA[kt]);
      }
    }
    __builtin_amdgcn_s_setprio(0);
    // mask: S^T value (kt,rr): key = k0+kt*16+quad*4+rr, query = qX0+w*16+l16
    if (maskB) {
      int qg = qb0 + (w << 4) + l16 + 128;
#pragma unroll
      for (int kt = 0; kt < 4; ++kt)
#pragma unroll
        for (int rr = 0; rr < 4; ++rr) {
          int kg = k0 + (kt << 4) + (quad << 2) + rr;
          if (kg > qg) sB[kt][rr] = -1e30f;
        }
    }
    if constexpr (BOTH) {
      if (maskA) {
        int qg = qa0 + (w << 4) + l16 + 128;
#pragma unroll
        for (int kt = 0; kt < 4; ++kt)
#pragma unroll
          for (int rr = 0; rr < 4; ++rr) {
            int kg = k0 + (kt << 4) + (quad << 2) + rr;
            if (kg > qg) sA[kt][rr] = -1e30f;
          }
      }
    }
    // exp2 + packed bf16x2 words, fully in registers
    unsigned wBp[4][2], wAp[4][2];
#pragma unroll
    for (int kt = 0; kt < 4; ++kt) {
      float p0 = exp2f(sB[kt][0]), p1 = exp2f(sB[kt][1]);
      float p2 = exp2f(sB[kt][2]), p3 = exp2f(sB[kt][3]);
      lB += (p0 + p1) + (p2 + p3);
      wBp[kt][0] = pk_bf16(p0, p1);
      wBp[kt][1] = pk_bf16(p2, p3);
      if constexpr (BOTH) {
        float a0 = exp2f(sA[kt][0]), a1 = exp2f(sA[kt][1]);
        float a2 = exp2f(sA[kt][2]), a3 = exp2f(sA[kt][3]);
        lA += (a0 + a1) + (a2 + a3);
        wAp[kt][0] = pk_bf16(a0, a1);
        wAp[kt][1] = pk_bf16(a2, a3);
      }
    }
    // PV: build P A-fragments via permlane swaps; shared vf feeds both
#pragma unroll
    for (int kcl = 0; kcl < 2; ++kcl) {
      unsigned a0 = wBp[2 * kcl][0], a1 = wBp[2 * kcl][1];
      unsigned b0 = wBp[2 * kcl + 1][0], b1 = wBp[2 * kcl + 1][1];
      swap32(a0, b0); swap16(a0, b0);   // a0 = W0, b0 = W2
      swap32(a1, b1); swap16(a1, b1);   // a1 = W1, b1 = W3
      short8 pfB = mk_frag(a0, a1, b0, b1);
      short8 pfA;
      if constexpr (BOTH) {
        unsigned c0 = wAp[2 * kcl][0], c1 = wAp[2 * kcl][1];
        unsigned d0 = wAp[2 * kcl + 1][0], d1 = wAp[2 * kcl + 1][1];
        swap32(c0, d0); swap16(c0, d0);
        swap32(c1, d1); swap16(c1, d1);
        pfA = mk_frag(c0, c1, d0, d1);
      }
      int g = (kcl << 2) + quad;
      __builtin_amdgcn_s_setprio(1);
#pragma unroll
      for (int nd = 0; nd < 8; ++nd) {
        int vrow = (nd << 4) + l16;
        int vpos = g ^ (vrow & 7);
        short8 vf = *(const short8*)(lvb + vrow * 64 + (vpos << 3));
        oB[nd] = mfma16(pfB, vf, oB[nd]);
        if constexpr (BOTH) oA[nd] = mfma16(pfA, vf, oA[nd]);
      }
      __builtin_amdgcn_s_setprio(0);
    }
  };

  stage(0, 0);
  __syncthreads();  // vmcnt(0) drain -> buf0 ready
  for (int j = 0; j < nkB; ++j) {
    if (j + 1 < nkB) stage(j + 1, (j + 1) & 1);  // prefetch overlaps compute
    const int k0 = j << 6;
    if (j < nkA)
      tile(std::integral_constant<bool, true>{}, k0, j == jmA, j == jmB, j & 1);
    else
      tile(std::integral_constant<bool, false>{}, k0, false, j == jmB, j & 1);
    __syncthreads();  // drains prefetch (had full compute phase in flight)
  }

  // l: sum quads (lanes sharing l16), invert, redistribute to (quad,rr) rows
  lA += __shfl_xor(lA, 16, 64); lA += __shfl_xor(lA, 32, 64);
  lB += __shfl_xor(lB, 16, 64); lB += __shfl_xor(lB, 32, 64);
  float liA = 1.0f / lA, liB = 1.0f / lB;
  float rlA[4], rlB[4];
#pragma unroll
  for (int rr = 0; rr < 4; ++rr) {
    int src = (quad << 2) + rr;
    rlA[rr] = __shfl(liA, src, 64);
    rlB[rr] = __shfl(liB, src, 64);
  }

  bf16* OpA = O + ((long)(b << 11) + qa0 + (w << 4)) * 2048 + (h << 7);
  bf16* OpB = O + ((long)(b << 11) + qb0 + (w << 4)) * 2048 + (h << 7);
#pragma unroll
  for (int nd = 0; nd < 8; ++nd)
#pragma unroll
    for (int rr = 0; rr < 4; ++rr) {
      int row = (quad << 2) + rr;
      int col = (nd << 4) + l16;
      OpA[(long)row * 2048 + col] = __float2bfloat16(oA[nd][rr] * rlA[rr]);
      OpB[(long)row * 2048 + col] = __float2bfloat16(oB[nd][rr] * rlB[rr]);
    }
}

extern "C" void kernel_launch(void* const* d_in, const int* in_sizes, int n_in,
                              void* d_out, int out_size, void* d_ws, size_t ws_size,
                              hipStream_t stream) {
  (void)in_sizes; (void)n_in; (void)out_size; (void)ws_size;
  const float* x  = (const float*)d_in[0];
  const float* Wq = (const float*)d_in[1];
  const float* Wk = (const float*)d_in[2];
  const float* Wv = (const float*)d_in[3];
  const float* Wo = (const float*)d_in[4];
  char* ws = (char*)d_ws;
  // ws layout (bytes): xb 16.7M | wqkv 12.6M | wo_b 8.4M | qkv 25.2M | Q 16.8M | K 4.2M | Vt 4.2M
  bf16* xb   = (bf16*)(ws);                 // also reused as Ob after gemm1
  bf16* wqkv = (bf16*)(ws + 16777216);
  bf16* wo_b = (bf16*)(ws + 29360128);
  bf16* qkv  = (bf16*)(ws + 37748736);
  bf16* Qr   = (bf16*)(ws + 62914560);
  bf16* Kr   = (bf16*)(ws + 79691776);
  bf16* Vt   = (bf16*)(ws + 83886080);
  bf16* Ob   = xb;  // x dead after QKV GEMM
  float* out = (float*)d_out;

  cast_all_k<<<18432, 256, 0, stream>>>(x, Wq, Wk, Wv, Wo, xb, wqkv, wo_b);

  gemm_bt<bf16><<<dim3(32, 24), 256, 0, stream>>>(xb, wqkv, qkv, 4096, 3072, 2048);
  rope_vt_k<<<4608, 256, 0, stream>>>(qkv, Qr, Kr, Vt);
  attn_k<<<dim3(512), 256, 0, stream>>>(Qr, Kr, Vt, Ob);
  gemm_bt<float><<<dim3(32, 16), 256, 0, stream>>>(Ob, wo_b, out, 4096, 2048, 2048);
}